// Round 11
// baseline (28392.169 us; speedup 1.0000x reference)
//
#include <hip/hip_runtime.h>
#include <stdint.h>

typedef unsigned short ushort_t;
typedef unsigned long long u64;
typedef __attribute__((ext_vector_type(8))) short short8;
typedef __attribute__((ext_vector_type(4))) float f32x4;
typedef __attribute__((ext_vector_type(4))) unsigned int u32x4;

#define WS_W0T_HI 0u
#define WS_W0T_LO (2u<<20)
#define WS_WST_HI (4u<<20)
#define WS_WST_LO (12u<<20)
#define WS_ST     (20u<<20)
#define WS_BAR    (26u<<20)

#define SLOT_ELEMS 262144   // per state slot (hi+lo bf16 planes), elements
#define PLANE 131072        // 256*512

// state slots (bf16 hi/lo planes, LINEAR layout): 0=h,1=s0,2=s1,3=s2,4=s3,5=s5

__device__ __forceinline__ ushort_t f2bf(float f) {
  unsigned u = __float_as_uint(f);
  u += 0x7FFFu + ((u >> 16) & 1u);          // RNE to bf16
  return (ushort_t)(u >> 16);
}
__device__ __forceinline__ float bf2f(ushort_t h) {
  return __uint_as_float(((unsigned)h) << 16);
}
__device__ __forceinline__ float sigf(float v) { return 1.f / (1.f + __expf(-v)); }

// 16B uncached load (bypass L1/L2, coherent at L3)
__device__ __forceinline__ u32x4 uld16(const void* p) {
  u32x4 r;
  asm volatile("global_load_dwordx4 %0, %1, off sc0 sc1" : "=v"(r) : "v"(p));
  return r;
}

// paired-column state store (uncached 4B words), linear layout
__device__ __forceinline__ void st_state(ushort_t* slot, int eo, float s, int tid) {
  ushort_t hi = f2bf(s);
  ushort_t lo = f2bf(s - bf2f(hi));
  unsigned nh = __shfl_xor((unsigned)hi, 1, 64);
  unsigned nl = __shfl_xor((unsigned)lo, 1, 64);
  if (!(tid & 1)) {
    unsigned wh = (unsigned)hi | (nh << 16);
    unsigned wl = (unsigned)lo | (nl << 16);
    __hip_atomic_store((unsigned*)(slot + eo), wh, __ATOMIC_RELAXED, __HIP_MEMORY_SCOPE_AGENT);
    __hip_atomic_store((unsigned*)(slot + PLANE + eo), wl, __ATOMIC_RELAXED, __HIP_MEMORY_SCOPE_AGENT);
  }
}

// convert 8 f32 (cached loads) -> bf16 hi/lo fragments (stage A x-path)
__device__ __forceinline__ void xcvt(const float* xp, short8& ah, short8& al) {
  f32x4 v0 = *(const f32x4*)xp;
  f32x4 v1 = *(const f32x4*)(xp + 4);
#pragma unroll
  for (int i = 0; i < 4; ++i) {
    ushort_t h0 = f2bf(v0[i]);
    ah[i] = (short)h0; al[i] = (short)f2bf(v0[i] - bf2f(h0));
    ushort_t h1 = f2bf(v1[i]);
    ah[i + 4] = (short)h1; al[i + 4] = (short)f2bf(v1[i] - bf2f(h1));
  }
}

// ---------------- prep: transpose + hi/lo split weights; convert h0 ---------
extern "C" __global__ void prep_kernel(const float* __restrict__ W0,
                                       const float* __restrict__ Ws,
                                       const float* __restrict__ h0,
                                       char* __restrict__ ws) {
  ushort_t* w0h = (ushort_t*)(ws + WS_W0T_HI);
  ushort_t* w0l = (ushort_t*)(ws + WS_W0T_LO);
  ushort_t* wsh = (ushort_t*)(ws + WS_WST_HI);
  ushort_t* wsl = (ushort_t*)(ws + WS_WST_LO);
  ushort_t* st  = (ushort_t*)(ws + WS_ST);
  const long N0 = 1048576, N1 = 4194304, N2 = 131072;
  long total = N0 + N1 + N2;
  for (long idx = (long)blockIdx.x * blockDim.x + threadIdx.x; idx < total;
       idx += (long)gridDim.x * blockDim.x) {
    if (idx < N0) {                       // W0T[j][k] from W0[k][j], K=1024
      int k = (int)(idx >> 10), j = (int)(idx & 1023);
      float v = W0[k * 1024 + j];
      ushort_t hi = f2bf(v);
      w0h[j * 1024 + k] = hi;
      w0l[j * 1024 + k] = f2bf(v - bf2f(hi));
    } else if (idx < N0 + N1) {           // WsT[i][j][k] from Ws[i][k][j], K=512
      long r = idx - N0;
      int i = (int)(r >> 19);
      int r2 = (int)(r & 524287);
      int k = r2 >> 10, j = r2 & 1023;
      float v = Ws[(long)i * 524288 + k * 1024 + j];
      ushort_t hi = f2bf(v);
      wsh[(long)i * 524288 + j * 512 + k] = hi;
      wsl[(long)i * 524288 + j * 512 + k] = f2bf(v - bf2f(hi));
    } else {                              // h0 -> slot 0 (linear)
      int e = (int)(idx - N0 - N1);
      float v = h0[e];
      ushort_t hi = f2bf(v);
      st[e] = hi;
      st[PLANE + e] = f2bf(v - bf2f(hi));
    }
  }
}

// ---- producer-flag sync ----------------------------------------------------
__device__ __forceinline__ void set_flag(unsigned* flags, int g, int pt, unsigned gen) {
  __syncthreads();   // drains each wave's vmcnt: uncached stores coherent-visible
  if (threadIdx.x == 0)
    __hip_atomic_store(flags + (g * 32 + pt) * 16, gen, __ATOMIC_RELAXED, __HIP_MEMORY_SCOPE_AGENT);
}
// each thread polls the 2 producers of its panel chunks
__device__ __forceinline__ void panel_poll2(const unsigned* flags, int g, unsigned G, int tid) {
  const int i2 = (tid & 31) >> 1;
  const unsigned* f0 = flags + (g * 32 + i2) * 16;
  const unsigned* f1 = flags + (g * 32 + 16 + i2) * 16;
  while (__hip_atomic_load(f0, __ATOMIC_RELAXED, __HIP_MEMORY_SCOPE_AGENT) < G)
    __builtin_amdgcn_s_sleep(2);
  while (__hip_atomic_load(f1, __ATOMIC_RELAXED, __HIP_MEMORY_SCOPE_AGENT) < G)
    __builtin_amdgcn_s_sleep(2);
}

// ---- panel: [kc(64)][rowslot(16)][8] shorts, XOR-swizzled rowslot = row^(kc&15)
// 16 rows x 512 cols, hi/lo planes. Producer writes & consumer reads both ~2-way.
__device__ __forceinline__ void panel_copy(const ushort_t* slot, int r0,
                                           ushort_t* Ph, ushort_t* Pl, int tid) {
  const int row = tid >> 5, i = tid & 31;
  const ushort_t* src = slot + (r0 + row) * 512;
  u32x4 h0 = uld16(src + i * 8);
  u32x4 h1 = uld16(src + 256 + i * 8);
  u32x4 l0 = uld16(src + PLANE + i * 8);
  u32x4 l1 = uld16(src + PLANE + 256 + i * 8);
  asm volatile("s_waitcnt vmcnt(0)" ::: "memory");
  __builtin_amdgcn_sched_barrier(0);      // rule #18: pin consumers after waitcnt
  const int kc0 = i, kc1 = i + 32;
  *(u32x4*)(Ph + kc0 * 128 + ((row ^ (kc0 & 15)) << 3)) = h0;
  *(u32x4*)(Ph + kc1 * 128 + ((row ^ (kc1 & 15)) << 3)) = h1;
  *(u32x4*)(Pl + kc0 * 128 + ((row ^ (kc0 & 15)) << 3)) = l0;
  *(u32x4*)(Pl + kc1 * 128 + ((row ^ (kc1 & 15)) << 3)) = l1;
}

__device__ __forceinline__ f32x4 mfma3_4(short8 ah, short8 al, short8 bh, short8 bl, f32x4 acc) {
  acc = __builtin_amdgcn_mfma_f32_16x16x32_bf16(ah, bh, acc, 0, 0, 0);
  acc = __builtin_amdgcn_mfma_f32_16x16x32_bf16(ah, bl, acc, 0, 0, 0);
  acc = __builtin_amdgcn_mfma_f32_16x16x32_bf16(al, bh, acc, 0, 0, 0);
  return acc;
}

// K=512 (per-wave K=64 slice): A-frags from swizzled panel, B from linear W^T.
// b0/b1 = column-base offsets for ct=0 (c half) / ct=1 (h half), incl. K-add.
template<int NP>
__device__ __forceinline__ void mm16(const ushort_t* Ph, const ushort_t* Pl,
                                     const ushort_t* const (&wh)[NP],
                                     const ushort_t* const (&wl)[NP],
                                     int b0, int b1, int w, int lane,
                                     f32x4 (&acc)[NP][2]) {
#pragma unroll
  for (int kb = 0; kb < 2; ++kb) {
    const int ko = w * 64 + kb * 32 + ((lane >> 4) << 3);
    const int kc = ko >> 3;
    const int po = kc * 128 + (((lane & 15) ^ (kc & 15)) << 3);
    short8 ah = *(const short8*)(Ph + po);
    short8 al = *(const short8*)(Pl + po);
#pragma unroll
    for (int p = 0; p < NP; ++p) {
      short8 bh0 = *(const short8*)(wh[p] + b0 + ko);
      short8 bl0 = *(const short8*)(wl[p] + b0 + ko);
      acc[p][0] = mfma3_4(ah, al, bh0, bl0, acc[p][0]);
      short8 bh1 = *(const short8*)(wh[p] + b1 + ko);
      short8 bl1 = *(const short8*)(wl[p] + b1 + ko);
      acc[p][1] = mfma3_4(ah, al, bh1, bl1, acc[p][1]);
    }
  }
}

// pp[w*2+ct][16][18] f32 — 16x16 C/D layout: col=lane&15, row=(lane>>4)*4+r
__device__ __forceinline__ void wr16(float* pp, int ct, const f32x4& a, int w, int lane) {
  float* b = pp + (w * 2 + ct) * 288 + (lane & 15);
  const int rb = (lane >> 4) * 4;
#pragma unroll
  for (int r = 0; r < 4; ++r) b[(rb + r) * 18] = a[r];
}
__device__ __forceinline__ void rd2(const float* pp, int erow, int ep,
                                    float& c, float& h) {
  float cs = 0.f, hs = 0.f;
#pragma unroll
  for (int w = 0; w < 8; ++w) {
    cs += pp[(w * 2 + 0) * 288 + erow * 18 + ep];
    hs += pp[(w * 2 + 1) * 288 + erow * 18 + ep];
  }
  c = cs; h = hs;
}

// ---------------- main persistent kernel (2 WGs/CU) ------------------------
extern "C" __global__ void __launch_bounds__(512, 4)
rnn_main(const float* __restrict__ x, float* __restrict__ out, char* __restrict__ ws) {
  __shared__ __align__(16) ushort_t Ph[8192];   // 16 KB panel hi (swizzled)
  __shared__ __align__(16) ushort_t Pl[8192];   // 16 KB panel lo
  __shared__ __align__(16) float pp0[4608];     // 18 KB partials (matrix 0)
  __shared__ __align__(16) float pp1[4608];     // 18 KB partials (matrix 1)

  ushort_t* stg = (ushort_t*)(ws + WS_ST);
  unsigned* flags = (unsigned*)(ws + WS_BAR);
  const ushort_t* w0h = (const ushort_t*)(ws + WS_W0T_HI);
  const ushort_t* w0l = (const ushort_t*)(ws + WS_W0T_LO);
  const ushort_t* wsh = (const ushort_t*)(ws + WS_WST_HI);
  const ushort_t* wsl = (const ushort_t*)(ws + WS_WST_LO);

  const int tid = threadIdx.x;
  const int wg = blockIdx.x;
  const int g = wg >> 5, pt = wg & 31;    // 16 row-groups x 32 col-WGs; XCD = pt%8
  const int r0 = g * 16;
  const int w = tid >> 6, lane = tid & 63;
  const int jA = pt * 16 + (lane & 15);   // this lane's weight column (c half)
  const int b5_0 = jA * 512,  b5_1 = (jA + 512) * 512;          // Ws matrices
  const int bA_0 = jA * 1024 + 512, bA_1 = (jA + 512) * 1024 + 512;  // W0 h-part

  const int erow = tid >> 4, ep = tid & 15;        // epilogue coords (tid<256)
  const int eo = (r0 + erow) * 512 + pt * 16 + ep;

  float h_reg = 0.f, s0_r = 0.f, s1_r = 0.f, s2_r = 0.f, s3_r = 0.f, s5_r = 0.f, sum = 0.f;
  if (tid < 256) h_reg = bf2f(stg[eo]) + bf2f(stg[PLANE + eo]);

  for (int t = 0; t < 400; ++t) {
    const unsigned base = 5u * (unsigned)t;

    // ===== stage A: s0 = h + sig(c)*(tanh(hh) - h), A=[x|h], W0 ============
    {
      f32x4 acc[1][2] = {};
      // x-part (K 0..511): cached loads, no flag dependency — overlaps producers
      const float* xr = x + (size_t)t * 131072 + (size_t)(r0 + (lane & 15)) * 512;
#pragma unroll
      for (int kb = 0; kb < 2; ++kb) {
        const int ko = w * 64 + kb * 32 + ((lane >> 4) << 3);
        short8 xh, xl; xcvt(xr + ko, xh, xl);
        short8 bh0 = *(const short8*)(w0h + jA * 1024 + ko);
        short8 bl0 = *(const short8*)(w0l + jA * 1024 + ko);
        acc[0][0] = mfma3_4(xh, xl, bh0, bl0, acc[0][0]);
        short8 bh1 = *(const short8*)(w0h + (jA + 512) * 1024 + ko);
        short8 bl1 = *(const short8*)(w0l + (jA + 512) * 1024 + ko);
        acc[0][1] = mfma3_4(xh, xl, bh1, bl1, acc[0][1]);
      }
      panel_poll2(flags, g, base, tid);   // E flags of t-1 (h producers)
      panel_copy(stg + 0 * SLOT_ELEMS, r0, Ph, Pl, tid);
      __syncthreads();
      const ushort_t* wh1[1] = {w0h};
      const ushort_t* wl1[1] = {w0l};
      mm16<1>(Ph, Pl, wh1, wl1, bA_0, bA_1, w, lane, acc);
      wr16(pp0, 0, acc[0][0], w, lane);
      wr16(pp0, 1, acc[0][1], w, lane);
      __syncthreads();
      if (tid < 256) {
        float c, hh; rd2(pp0, erow, ep, c, hh);
        s0_r = h_reg + sigf(c) * (tanhf(hh) - h_reg);
        st_state(stg + 1 * SLOT_ELEMS, eo, s0_r, tid);
      }
    }
    set_flag(flags, g, pt, base + 1);

    // ===== stage B: s1 = f(s0, tanh, Ws[0]) ================================
    {
      panel_poll2(flags, g, base + 1, tid);
      panel_copy(stg + 1 * SLOT_ELEMS, r0, Ph, Pl, tid);
      __syncthreads();
      f32x4 acc[1][2] = {};
      const ushort_t* wh1[1] = {wsh + 0 * 524288};
      const ushort_t* wl1[1] = {wsl + 0 * 524288};
      mm16<1>(Ph, Pl, wh1, wl1, b5_0, b5_1, w, lane, acc);
      wr16(pp0, 0, acc[0][0], w, lane);
      wr16(pp0, 1, acc[0][1], w, lane);
      __syncthreads();
      if (tid < 256) {
        float c, hh; rd2(pp0, erow, ep, c, hh);
        s1_r = s0_r + sigf(c) * (tanhf(hh) - s0_r);
        sum = s1_r;
        st_state(stg + 2 * SLOT_ELEMS, eo, s1_r, tid);
      }
    }
    set_flag(flags, g, pt, base + 2);

    // ===== stage C: s2(relu,Ws1) s3(relu,Ws2) s4(ident,Ws3) from s1 ========
    {
      panel_poll2(flags, g, base + 2, tid);
      panel_copy(stg + 2 * SLOT_ELEMS, r0, Ph, Pl, tid);
      __syncthreads();
      f32x4 acc[3][2] = {};
      const ushort_t* wh3[3] = {wsh + 1 * 524288, wsh + 2 * 524288, wsh + 3 * 524288};
      const ushort_t* wl3[3] = {wsl + 1 * 524288, wsl + 2 * 524288, wsl + 3 * 524288};
      mm16<3>(Ph, Pl, wh3, wl3, b5_0, b5_1, w, lane, acc);
      wr16(pp0, 0, acc[0][0], w, lane);   // s2
      wr16(pp0, 1, acc[0][1], w, lane);
      wr16(pp1, 0, acc[1][0], w, lane);   // s3
      wr16(pp1, 1, acc[1][1], w, lane);
      __syncthreads();
      if (tid < 256) {
        float c, hh;
        rd2(pp0, erow, ep, c, hh);
        s2_r = s1_r + sigf(c) * (fmaxf(hh, 0.f) - s1_r);
        sum += s2_r;
        st_state(stg + 3 * SLOT_ELEMS, eo, s2_r, tid);
        rd2(pp1, erow, ep, c, hh);
        s3_r = s1_r + sigf(c) * (fmaxf(hh, 0.f) - s1_r);
        sum += s3_r;
        st_state(stg + 4 * SLOT_ELEMS, eo, s3_r, tid);
      }
      set_flag(flags, g, pt, base + 3);   // early: D needs only s2/s3
      wr16(pp0, 0, acc[2][0], w, lane);   // s4: concat-only
      wr16(pp0, 1, acc[2][1], w, lane);
      __syncthreads();
      if (tid < 256) {
        float c, hh; rd2(pp0, erow, ep, c, hh);
        sum += s1_r + sigf(c) * (hh - s1_r);
      }
    }

    // ===== stage D: s5 = f(s2,tanh,Ws4); s7 = f(s3,tanh,Ws6) — one poll ====
    {
      panel_poll2(flags, g, base + 3, tid);
      panel_copy(stg + 3 * SLOT_ELEMS, r0, Ph, Pl, tid);    // s2 panel
      __syncthreads();                    // also fences s4's pp0 reads
      f32x4 acc5[1][2] = {};
      const ushort_t* wh4[1] = {wsh + 4 * 524288};
      const ushort_t* wl4[1] = {wsl + 4 * 524288};
      mm16<1>(Ph, Pl, wh4, wl4, b5_0, b5_1, w, lane, acc5);
      wr16(pp0, 0, acc5[0][0], w, lane);
      wr16(pp0, 1, acc5[0][1], w, lane);
      __syncthreads();                    // panel reads done before recopy
      panel_copy(stg + 4 * SLOT_ELEMS, r0, Ph, Pl, tid);    // s3 panel
      __syncthreads();
      f32x4 acc7[1][2] = {};
      const ushort_t* wh6[1] = {wsh + 6 * 524288};
      const ushort_t* wl6[1] = {wsl + 6 * 524288};
      mm16<1>(Ph, Pl, wh6, wl6, b5_0, b5_1, w, lane, acc7);
      wr16(pp1, 0, acc7[0][0], w, lane);
      wr16(pp1, 1, acc7[0][1], w, lane);
      __syncthreads();
      if (tid < 256) {
        float c, hh;
        rd2(pp0, erow, ep, c, hh);
        s5_r = s2_r + sigf(c) * (tanhf(hh) - s2_r);
        sum += s5_r;
        st_state(stg + 5 * SLOT_ELEMS, eo, s5_r, tid);
        rd2(pp1, erow, ep, c, hh);        // s7: concat-only
        sum += s3_r + sigf(c) * (tanhf(hh) - s3_r);
      }
    }
    set_flag(flags, g, pt, base + 4);

    // ===== stage E: s6(sigmoid,Ws5) s8(relu,Ws7) from s5; mean; h ==========
    {
      panel_poll2(flags, g, base + 4, tid);
      panel_copy(stg + 5 * SLOT_ELEMS, r0, Ph, Pl, tid);
      __syncthreads();
      f32x4 acc[2][2] = {};
      const ushort_t* wh2[2] = {wsh + 5 * 524288, wsh + 7 * 524288};
      const ushort_t* wl2[2] = {wsl + 5 * 524288, wsl + 7 * 524288};
      mm16<2>(Ph, Pl, wh2, wl2, b5_0, b5_1, w, lane, acc);
      wr16(pp0, 0, acc[0][0], w, lane);   // s6
      wr16(pp0, 1, acc[0][1], w, lane);
      wr16(pp1, 0, acc[1][0], w, lane);   // s8
      wr16(pp1, 1, acc[1][1], w, lane);
      __syncthreads();
      if (tid < 256) {
        float c, hh;
        rd2(pp0, erow, ep, c, hh);
        sum += s5_r + sigf(c) * (sigf(hh) - s5_r);
        rd2(pp1, erow, ep, c, hh);
        sum += s5_r + sigf(c) * (fmaxf(hh, 0.f) - s5_r);
        h_reg = sum * 0.125f;
        __builtin_nontemporal_store(h_reg, &out[(size_t)t * 131072 + eo]);
        if (t == 399)
          __builtin_nontemporal_store(h_reg, &out[(size_t)400 * 131072 + eo]);
        st_state(stg + 0 * SLOT_ELEMS, eo, h_reg, tid);
      }
    }
    set_flag(flags, g, pt, base + 5);
  }
}

// ---------------- host launch ----------------------------------------------
extern "C" void kernel_launch(void* const* d_in, const int* in_sizes, int n_in,
                              void* d_out, int out_size, void* d_ws, size_t ws_size,
                              hipStream_t stream) {
  const float* x  = (const float*)d_in[0];
  const float* h0 = (const float*)d_in[1];
  const float* W0 = (const float*)d_in[2];
  const float* Ws = (const float*)d_in[3];
  float* out = (float*)d_out;
  char* ws = (char*)d_ws;

  (void)in_sizes; (void)n_in; (void)out_size; (void)ws_size;

  (void)hipMemsetAsync(ws + WS_BAR, 0, 32768, stream);
  hipLaunchKernelGGL(prep_kernel, dim3(2048), dim3(256), 0, stream, W0, Ws, h0, ws);

  void* args[3] = {(void*)&x, (void*)&out, (void*)&ws};
  hipError_t e = hipLaunchCooperativeKernel((void*)rnn_main, dim3(512), dim3(512),
                                            args, 0, stream);
  if (e != hipSuccess) {
    (void)hipGetLastError();   // clear sticky error; fall back to plain launch.
    // 512 blocks x (69.6KB LDS, 128 VGPR) = 2/CU capacity on 256 CUs: all
    // blocks co-resident; flag protocol needs no grid-wide barrier.
    hipLaunchKernelGGL(rnn_main, dim3(512), dim3(512), 0, stream, x, out, ws);
  }
}

// Round 12
// 28199.643 us; speedup vs baseline: 1.0068x; 1.0068x over previous
//
#include <hip/hip_runtime.h>
#include <stdint.h>

typedef unsigned short ushort_t;
typedef unsigned long long u64;
typedef __attribute__((ext_vector_type(8))) short short8;
typedef __attribute__((ext_vector_type(4))) float f32x4;
typedef __attribute__((ext_vector_type(4))) unsigned int u32x4;

#define WS_W0T_HI 0u
#define WS_W0T_LO (2u<<20)
#define WS_WST_HI (4u<<20)
#define WS_WST_LO (12u<<20)
#define WS_ST     (20u<<20)
#define WS_BAR    (26u<<20)

#define SLOT_ELEMS 262144   // per state slot (hi+lo bf16 planes), elements
#define PLANE 131072        // 256*512

// state slots (bf16 hi/lo planes, LINEAR layout): 0=h,1=s0,2=s1,3=s2,4=s3,5=s5

__device__ __forceinline__ ushort_t f2bf(float f) {
  unsigned u = __float_as_uint(f);
  u += 0x7FFFu + ((u >> 16) & 1u);          // RNE to bf16
  return (ushort_t)(u >> 16);
}
__device__ __forceinline__ float bf2f(ushort_t h) {
  return __uint_as_float(((unsigned)h) << 16);
}
__device__ __forceinline__ float sigf(float v) { return 1.f / (1.f + __expf(-v)); }

// 16B uncached load (bypass L1/L2, coherent at L3)
__device__ __forceinline__ u32x4 uld16(const void* p) {
  u32x4 r;
  asm volatile("global_load_dwordx4 %0, %1, off sc0 sc1" : "=v"(r) : "v"(p));
  return r;
}

// paired-column state store (uncached 4B words), linear layout
__device__ __forceinline__ void st_state(ushort_t* slot, int eo, float s, int tid) {
  ushort_t hi = f2bf(s);
  ushort_t lo = f2bf(s - bf2f(hi));
  unsigned nh = __shfl_xor((unsigned)hi, 1, 64);
  unsigned nl = __shfl_xor((unsigned)lo, 1, 64);
  if (!(tid & 1)) {
    unsigned wh = (unsigned)hi | (nh << 16);
    unsigned wl = (unsigned)lo | (nl << 16);
    __hip_atomic_store((unsigned*)(slot + eo), wh, __ATOMIC_RELAXED, __HIP_MEMORY_SCOPE_AGENT);
    __hip_atomic_store((unsigned*)(slot + PLANE + eo), wl, __ATOMIC_RELAXED, __HIP_MEMORY_SCOPE_AGENT);
  }
}

// convert 8 f32 (cached loads) -> bf16 hi/lo fragments (stage A x-path)
__device__ __forceinline__ void xcvt(const float* xp, short8& ah, short8& al) {
  f32x4 v0 = *(const f32x4*)xp;
  f32x4 v1 = *(const f32x4*)(xp + 4);
#pragma unroll
  for (int i = 0; i < 4; ++i) {
    ushort_t h0 = f2bf(v0[i]);
    ah[i] = (short)h0; al[i] = (short)f2bf(v0[i] - bf2f(h0));
    ushort_t h1 = f2bf(v1[i]);
    ah[i + 4] = (short)h1; al[i + 4] = (short)f2bf(v1[i] - bf2f(h1));
  }
}

// ---------------- prep: transpose + hi/lo split weights; convert h0 ---------
extern "C" __global__ void prep_kernel(const float* __restrict__ W0,
                                       const float* __restrict__ Ws,
                                       const float* __restrict__ h0,
                                       char* __restrict__ ws) {
  ushort_t* w0h = (ushort_t*)(ws + WS_W0T_HI);
  ushort_t* w0l = (ushort_t*)(ws + WS_W0T_LO);
  ushort_t* wsh = (ushort_t*)(ws + WS_WST_HI);
  ushort_t* wsl = (ushort_t*)(ws + WS_WST_LO);
  ushort_t* st  = (ushort_t*)(ws + WS_ST);
  const long N0 = 1048576, N1 = 4194304, N2 = 131072;
  long total = N0 + N1 + N2;
  for (long idx = (long)blockIdx.x * blockDim.x + threadIdx.x; idx < total;
       idx += (long)gridDim.x * blockDim.x) {
    if (idx < N0) {                       // W0T[j][k] from W0[k][j], K=1024
      int k = (int)(idx >> 10), j = (int)(idx & 1023);
      float v = W0[k * 1024 + j];
      ushort_t hi = f2bf(v);
      w0h[j * 1024 + k] = hi;
      w0l[j * 1024 + k] = f2bf(v - bf2f(hi));
    } else if (idx < N0 + N1) {           // WsT[i][j][k] from Ws[i][k][j], K=512
      long r = idx - N0;
      int i = (int)(r >> 19);
      int r2 = (int)(r & 524287);
      int k = r2 >> 10, j = r2 & 1023;
      float v = Ws[(long)i * 524288 + k * 1024 + j];
      ushort_t hi = f2bf(v);
      wsh[(long)i * 524288 + j * 512 + k] = hi;
      wsl[(long)i * 524288 + j * 512 + k] = f2bf(v - bf2f(hi));
    } else {                              // h0 -> slot 0 (linear)
      int e = (int)(idx - N0 - N1);
      float v = h0[e];
      ushort_t hi = f2bf(v);
      st[e] = hi;
      st[PLANE + e] = f2bf(v - bf2f(hi));
    }
  }
}

// ---- producer-flag sync ----------------------------------------------------
__device__ __forceinline__ void set_flag(unsigned* flags, int g, int pt, unsigned gen) {
  __syncthreads();   // drains each wave's vmcnt: uncached stores coherent-visible
  if (threadIdx.x == 0)
    __hip_atomic_store(flags + (g * 32 + pt) * 16, gen, __ATOMIC_RELAXED, __HIP_MEMORY_SCOPE_AGENT);
}
// each thread polls the 2 producers of its panel chunks
__device__ __forceinline__ void panel_poll2(const unsigned* flags, int g, unsigned G, int tid) {
  const int i2 = (tid & 31) >> 1;
  const unsigned* f0 = flags + (g * 32 + i2) * 16;
  const unsigned* f1 = flags + (g * 32 + 16 + i2) * 16;
  while (__hip_atomic_load(f0, __ATOMIC_RELAXED, __HIP_MEMORY_SCOPE_AGENT) < G)
    __builtin_amdgcn_s_sleep(2);
  while (__hip_atomic_load(f1, __ATOMIC_RELAXED, __HIP_MEMORY_SCOPE_AGENT) < G)
    __builtin_amdgcn_s_sleep(2);
}

// ---- panel: [kc(64)][rowslot(16)][8] shorts, XOR-swizzled rowslot = row^(kc&15)
__device__ __forceinline__ void panel_copy(const ushort_t* slot, int r0,
                                           ushort_t* Ph, ushort_t* Pl, int tid) {
  const int row = tid >> 5, i = tid & 31;
  const ushort_t* src = slot + (r0 + row) * 512;
  u32x4 h0 = uld16(src + i * 8);
  u32x4 h1 = uld16(src + 256 + i * 8);
  u32x4 l0 = uld16(src + PLANE + i * 8);
  u32x4 l1 = uld16(src + PLANE + 256 + i * 8);
  asm volatile("s_waitcnt vmcnt(0)" ::: "memory");
  __builtin_amdgcn_sched_barrier(0);      // rule #18
  const int kc0 = i, kc1 = i + 32;
  *(u32x4*)(Ph + kc0 * 128 + ((row ^ (kc0 & 15)) << 3)) = h0;
  *(u32x4*)(Ph + kc1 * 128 + ((row ^ (kc1 & 15)) << 3)) = h1;
  *(u32x4*)(Pl + kc0 * 128 + ((row ^ (kc0 & 15)) << 3)) = l0;
  *(u32x4*)(Pl + kc1 * 128 + ((row ^ (kc1 & 15)) << 3)) = l1;
}

__device__ __forceinline__ f32x4 mfma3_4(short8 ah, short8 al, short8 bh, short8 bl, f32x4 acc) {
  acc = __builtin_amdgcn_mfma_f32_16x16x32_bf16(ah, bh, acc, 0, 0, 0);
  acc = __builtin_amdgcn_mfma_f32_16x16x32_bf16(ah, bl, acc, 0, 0, 0);
  acc = __builtin_amdgcn_mfma_f32_16x16x32_bf16(al, bh, acc, 0, 0, 0);
  return acc;
}

// K=512 (per-wave K=64 slice): A-frags from swizzled panel, B from linear W^T.
template<int NP>
__device__ __forceinline__ void mm16(const ushort_t* Ph, const ushort_t* Pl,
                                     const ushort_t* const (&wh)[NP],
                                     const ushort_t* const (&wl)[NP],
                                     int b0, int b1, int w, int lane,
                                     f32x4 (&acc)[NP][2]) {
#pragma unroll
  for (int kb = 0; kb < 2; ++kb) {
    const int ko = w * 64 + kb * 32 + ((lane >> 4) << 3);
    const int kc = ko >> 3;
    const int po = kc * 128 + (((lane & 15) ^ (kc & 15)) << 3);
    short8 ah = *(const short8*)(Ph + po);
    short8 al = *(const short8*)(Pl + po);
#pragma unroll
    for (int p = 0; p < NP; ++p) {
      short8 bh0 = *(const short8*)(wh[p] + b0 + ko);
      short8 bl0 = *(const short8*)(wl[p] + b0 + ko);
      acc[p][0] = mfma3_4(ah, al, bh0, bl0, acc[p][0]);
      short8 bh1 = *(const short8*)(wh[p] + b1 + ko);
      short8 bl1 = *(const short8*)(wl[p] + b1 + ko);
      acc[p][1] = mfma3_4(ah, al, bh1, bl1, acc[p][1]);
    }
  }
}

// pp[w*2+ct][16][18] f32 — 16x16 C/D layout: col=lane&15, row=(lane>>4)*4+r
__device__ __forceinline__ void wr16(float* pp, int ct, const f32x4& a, int w, int lane) {
  float* b = pp + (w * 2 + ct) * 288 + (lane & 15);
  const int rb = (lane >> 4) * 4;
#pragma unroll
  for (int r = 0; r < 4; ++r) b[(rb + r) * 18] = a[r];
}
__device__ __forceinline__ void rd2(const float* pp, int erow, int ep,
                                    float& c, float& h) {
  float cs = 0.f, hs = 0.f;
#pragma unroll
  for (int w = 0; w < 8; ++w) {
    cs += pp[(w * 2 + 0) * 288 + erow * 18 + ep];
    hs += pp[(w * 2 + 1) * 288 + erow * 18 + ep];
  }
  c = cs; h = hs;
}

// ---------------- main persistent kernel: 2 contexts per WG ----------------
extern "C" __global__ void __launch_bounds__(512, 1)
rnn_main(const float* __restrict__ x, float* __restrict__ out, char* __restrict__ ws) {
  __shared__ __align__(16) ushort_t Ph[8192];   // 16 KB panel hi (swizzled)
  __shared__ __align__(16) ushort_t Pl[8192];   // 16 KB panel lo
  __shared__ __align__(16) float pp0[4608];     // 18 KB partials (matrix 0)
  __shared__ __align__(16) float pp1[4608];     // 18 KB partials (matrix 1)

  ushort_t* stg = (ushort_t*)(ws + WS_ST);
  unsigned* flags = (unsigned*)(ws + WS_BAR);
  const ushort_t* w0h = (const ushort_t*)(ws + WS_W0T_HI);
  const ushort_t* w0l = (const ushort_t*)(ws + WS_W0T_LO);
  const ushort_t* wsh = (const ushort_t*)(ws + WS_WST_HI);
  const ushort_t* wsl = (const ushort_t*)(ws + WS_WST_LO);

  const int tid = threadIdx.x;
  const int wg = blockIdx.x;
  const int pt = wg & 31;                 // col-slice; XCD = wg%8 tracks pt%8
  const int gpair = wg >> 3;              // keep XCD grouping on wg%8
  // two independent 16-row contexts per WG: groups 2*(wg>>5), +1 — recompute:
  const int gA = ((wg >> 5) << 1), gB = gA + 1;   // 16 groups total
  (void)gpair;
  const int r0A = gA * 16, r0B = gB * 16;
  const int w = tid >> 6, lane = tid & 63;
  const int jA = pt * 16 + (lane & 15);
  const int b5_0 = jA * 512, b5_1 = (jA + 512) * 512;
  const int bA_0 = jA * 1024 + 512, bA_1 = (jA + 512) * 1024 + 512;
  const int erow = tid >> 4, ep = tid & 15;
  const int eoA = (r0A + erow) * 512 + pt * 16 + ep;
  const int eoB = (r0B + erow) * 512 + pt * 16 + ep;

  float hA = 0.f, hB = 0.f;
  if (tid < 256) {
    hA = bf2f(stg[eoA]) + bf2f(stg[PLANE + eoA]);
    hB = bf2f(stg[eoB]) + bf2f(stg[PLANE + eoB]);
  }
  float s0A = 0, s1A = 0, s2A = 0, s3A = 0, s5A = 0, sumA = 0;
  float s0B = 0, s1B = 0, s2B = 0, s3B = 0, s5B = 0, sumB = 0;

  int t = 0;

  // ---- stage lambdas (one context each; LDS time-shared, fenced by syncs) --
  auto stA = [&](int g, int r0, int eo, unsigned base, float& h_reg, float& s0_r) {
    f32x4 acc[1][2] = {};
    const float* xr = x + (size_t)t * 131072 + (size_t)(r0 + (lane & 15)) * 512;
#pragma unroll
    for (int kb = 0; kb < 2; ++kb) {      // x-part: cached, no flag dependency
      const int ko = w * 64 + kb * 32 + ((lane >> 4) << 3);
      short8 xh, xl; xcvt(xr + ko, xh, xl);
      short8 bh0 = *(const short8*)(w0h + jA * 1024 + ko);
      short8 bl0 = *(const short8*)(w0l + jA * 1024 + ko);
      acc[0][0] = mfma3_4(xh, xl, bh0, bl0, acc[0][0]);
      short8 bh1 = *(const short8*)(w0h + (jA + 512) * 1024 + ko);
      short8 bl1 = *(const short8*)(w0l + (jA + 512) * 1024 + ko);
      acc[0][1] = mfma3_4(xh, xl, bh1, bl1, acc[0][1]);
    }
    panel_poll2(flags, g, base, tid);     // E flags of t-1 (h producers)
    panel_copy(stg + 0 * SLOT_ELEMS, r0, Ph, Pl, tid);
    __syncthreads();
    const ushort_t* wh1[1] = {w0h};
    const ushort_t* wl1[1] = {w0l};
    mm16<1>(Ph, Pl, wh1, wl1, bA_0, bA_1, w, lane, acc);
    wr16(pp0, 0, acc[0][0], w, lane);
    wr16(pp0, 1, acc[0][1], w, lane);
    __syncthreads();
    if (tid < 256) {
      float c, hh; rd2(pp0, erow, ep, c, hh);
      s0_r = h_reg + sigf(c) * (tanhf(hh) - h_reg);
      st_state(stg + 1 * SLOT_ELEMS, eo, s0_r, tid);
    }
    set_flag(flags, g, pt, base + 1);
  };

  auto stB = [&](int g, int r0, int eo, unsigned base, float& s0_r, float& s1_r,
                 float& sum) {
    panel_poll2(flags, g, base + 1, tid);
    panel_copy(stg + 1 * SLOT_ELEMS, r0, Ph, Pl, tid);
    __syncthreads();
    f32x4 acc[1][2] = {};
    const ushort_t* wh1[1] = {wsh + 0 * 524288};
    const ushort_t* wl1[1] = {wsl + 0 * 524288};
    mm16<1>(Ph, Pl, wh1, wl1, b5_0, b5_1, w, lane, acc);
    wr16(pp0, 0, acc[0][0], w, lane);
    wr16(pp0, 1, acc[0][1], w, lane);
    __syncthreads();
    if (tid < 256) {
      float c, hh; rd2(pp0, erow, ep, c, hh);
      s1_r = s0_r + sigf(c) * (tanhf(hh) - s0_r);
      sum = s1_r;
      st_state(stg + 2 * SLOT_ELEMS, eo, s1_r, tid);
    }
    set_flag(flags, g, pt, base + 2);
  };

  auto stC = [&](int g, int r0, int eo, unsigned base, float& s1_r, float& s2_r,
                 float& s3_r, float& sum) {
    panel_poll2(flags, g, base + 2, tid);
    panel_copy(stg + 2 * SLOT_ELEMS, r0, Ph, Pl, tid);
    __syncthreads();
    f32x4 acc[3][2] = {};
    const ushort_t* wh3[3] = {wsh + 1 * 524288, wsh + 2 * 524288, wsh + 3 * 524288};
    const ushort_t* wl3[3] = {wsl + 1 * 524288, wsl + 2 * 524288, wsl + 3 * 524288};
    mm16<3>(Ph, Pl, wh3, wl3, b5_0, b5_1, w, lane, acc);
    wr16(pp0, 0, acc[0][0], w, lane);     // s2
    wr16(pp0, 1, acc[0][1], w, lane);
    wr16(pp1, 0, acc[1][0], w, lane);     // s3
    wr16(pp1, 1, acc[1][1], w, lane);
    __syncthreads();
    if (tid < 256) {
      float c, hh;
      rd2(pp0, erow, ep, c, hh);
      s2_r = s1_r + sigf(c) * (fmaxf(hh, 0.f) - s1_r);
      sum += s2_r;
      st_state(stg + 3 * SLOT_ELEMS, eo, s2_r, tid);
      rd2(pp1, erow, ep, c, hh);
      s3_r = s1_r + sigf(c) * (fmaxf(hh, 0.f) - s1_r);
      sum += s3_r;
      st_state(stg + 4 * SLOT_ELEMS, eo, s3_r, tid);
    }
    set_flag(flags, g, pt, base + 3);     // early: D needs only s2/s3
    wr16(pp0, 0, acc[2][0], w, lane);     // s4: concat-only
    wr16(pp0, 1, acc[2][1], w, lane);
    __syncthreads();
    if (tid < 256) {
      float c, hh; rd2(pp0, erow, ep, c, hh);
      sum += s1_r + sigf(c) * (hh - s1_r);
    }
  };

  auto stD = [&](int g, int r0, int eo, unsigned base, float& s2_r, float& s3_r,
                 float& s5_r, float& sum) {
    panel_poll2(flags, g, base + 3, tid);
    panel_copy(stg + 3 * SLOT_ELEMS, r0, Ph, Pl, tid);    // s2 panel
    __syncthreads();                      // also fences s4's pp0 reads
    f32x4 acc5[1][2] = {};
    const ushort_t* wh4[1] = {wsh + 4 * 524288};
    const ushort_t* wl4[1] = {wsl + 4 * 524288};
    mm16<1>(Ph, Pl, wh4, wl4, b5_0, b5_1, w, lane, acc5);
    wr16(pp0, 0, acc5[0][0], w, lane);
    wr16(pp0, 1, acc5[0][1], w, lane);
    __syncthreads();                      // panel reads done before recopy
    panel_copy(stg + 4 * SLOT_ELEMS, r0, Ph, Pl, tid);    // s3 panel
    __syncthreads();
    f32x4 acc7[1][2] = {};
    const ushort_t* wh6[1] = {wsh + 6 * 524288};
    const ushort_t* wl6[1] = {wsl + 6 * 524288};
    mm16<1>(Ph, Pl, wh6, wl6, b5_0, b5_1, w, lane, acc7);
    wr16(pp1, 0, acc7[0][0], w, lane);
    wr16(pp1, 1, acc7[0][1], w, lane);
    __syncthreads();
    if (tid < 256) {
      float c, hh;
      rd2(pp0, erow, ep, c, hh);
      s5_r = s2_r + sigf(c) * (tanhf(hh) - s2_r);
      sum += s5_r;
      st_state(stg + 5 * SLOT_ELEMS, eo, s5_r, tid);
      rd2(pp1, erow, ep, c, hh);          // s7: concat-only
      sum += s3_r + sigf(c) * (tanhf(hh) - s3_r);
    }
    set_flag(flags, g, pt, base + 4);
  };

  auto stE = [&](int g, int r0, int eo, unsigned base, float& s5_r, float& sum,
                 float& h_reg) {
    panel_poll2(flags, g, base + 4, tid);
    panel_copy(stg + 5 * SLOT_ELEMS, r0, Ph, Pl, tid);
    __syncthreads();
    f32x4 acc[2][2] = {};
    const ushort_t* wh2[2] = {wsh + 5 * 524288, wsh + 7 * 524288};
    const ushort_t* wl2[2] = {wsl + 5 * 524288, wsl + 7 * 524288};
    mm16<2>(Ph, Pl, wh2, wl2, b5_0, b5_1, w, lane, acc);
    wr16(pp0, 0, acc[0][0], w, lane);     // s6
    wr16(pp0, 1, acc[0][1], w, lane);
    wr16(pp1, 0, acc[1][0], w, lane);     // s8
    wr16(pp1, 1, acc[1][1], w, lane);
    __syncthreads();
    if (tid < 256) {
      float c, hh;
      rd2(pp0, erow, ep, c, hh);
      sum += s5_r + sigf(c) * (sigf(hh) - s5_r);
      rd2(pp1, erow, ep, c, hh);
      sum += s5_r + sigf(c) * (fmaxf(hh, 0.f) - s5_r);
      h_reg = sum * 0.125f;
      __builtin_nontemporal_store(h_reg, &out[(size_t)t * 131072 + eo]);
      if (t == 399)
        __builtin_nontemporal_store(h_reg, &out[(size_t)400 * 131072 + eo]);
      st_state(stg + 0 * SLOT_ELEMS, eo, h_reg, tid);
    }
    set_flag(flags, g, pt, base + 5);
  };

  for (t = 0; t < 400; ++t) {
    const unsigned base = 5u * (unsigned)t;
    stA(gA, r0A, eoA, base, hA, s0A);  stA(gB, r0B, eoB, base, hB, s0B);
    stB(gA, r0A, eoA, base, s0A, s1A, sumA);  stB(gB, r0B, eoB, base, s0B, s1B, sumB);
    stC(gA, r0A, eoA, base, s1A, s2A, s3A, sumA);
    stC(gB, r0B, eoB, base, s1B, s2B, s3B, sumB);
    stD(gA, r0A, eoA, base, s2A, s3A, s5A, sumA);
    stD(gB, r0B, eoB, base, s2B, s3B, s5B, sumB);
    stE(gA, r0A, eoA, base, s5A, sumA, hA);
    stE(gB, r0B, eoB, base, s5B, sumB, hB);
  }
}

// ---------------- host launch ----------------------------------------------
extern "C" void kernel_launch(void* const* d_in, const int* in_sizes, int n_in,
                              void* d_out, int out_size, void* d_ws, size_t ws_size,
                              hipStream_t stream) {
  const float* x  = (const float*)d_in[0];
  const float* h0 = (const float*)d_in[1];
  const float* W0 = (const float*)d_in[2];
  const float* Ws = (const float*)d_in[3];
  float* out = (float*)d_out;
  char* ws = (char*)d_ws;

  (void)in_sizes; (void)n_in; (void)out_size; (void)ws_size;

  (void)hipMemsetAsync(ws + WS_BAR, 0, 32768, stream);
  hipLaunchKernelGGL(prep_kernel, dim3(2048), dim3(256), 0, stream, W0, Ws, h0, ws);

  void* args[3] = {(void*)&x, (void*)&out, (void*)&ws};
  hipError_t e = hipLaunchCooperativeKernel((void*)rnn_main, dim3(256), dim3(512),
                                            args, 0, stream);
  if (e != hipSuccess) {
    (void)hipGetLastError();
    hipLaunchKernelGGL(rnn_main, dim3(256), dim3(512), 0, stream, x, out, ws);
  }
}

// Round 13
// 20031.648 us; speedup vs baseline: 1.4174x; 1.4078x over previous
//
#include <hip/hip_runtime.h>
#include <stdint.h>

typedef unsigned short ushort_t;
typedef unsigned long long u64;
typedef __attribute__((ext_vector_type(8))) short short8;
typedef __attribute__((ext_vector_type(4))) float f32x4;
typedef __attribute__((ext_vector_type(4))) unsigned int u32x4;

#define WS_W0T_HI 0u
#define WS_W0T_LO (2u<<20)
#define WS_WST_HI (4u<<20)
#define WS_WST_LO (12u<<20)
#define WS_ST     (20u<<20)
#define WS_BAR    (26u<<20)

#define SLOT_ELEMS 262144   // per state slot (hi+lo bf16 planes), elements
#define PLANE 131072        // 256*512

// state slots (bf16 hi/lo planes, LINEAR layout): 0=h,1=s0,2=s1,3=s2,4=s3,5=s5

__device__ __forceinline__ ushort_t f2bf(float f) {
  unsigned u = __float_as_uint(f);
  u += 0x7FFFu + ((u >> 16) & 1u);          // RNE to bf16
  return (ushort_t)(u >> 16);
}
__device__ __forceinline__ float bf2f(ushort_t h) {
  return __uint_as_float(((unsigned)h) << 16);
}
__device__ __forceinline__ float sigf(float v) { return 1.f / (1.f + __expf(-v)); }

// 16B uncached load (bypass L1/L2, coherent at L3)
__device__ __forceinline__ u32x4 uld16(const void* p) {
  u32x4 r;
  asm volatile("global_load_dwordx4 %0, %1, off sc0 sc1" : "=v"(r) : "v"(p));
  return r;
}

// paired-column state store (uncached 4B words), linear layout
__device__ __forceinline__ void st_state(ushort_t* slot, int eo, float s, int tid) {
  ushort_t hi = f2bf(s);
  ushort_t lo = f2bf(s - bf2f(hi));
  unsigned nh = __shfl_xor((unsigned)hi, 1, 64);
  unsigned nl = __shfl_xor((unsigned)lo, 1, 64);
  if (!(tid & 1)) {
    unsigned wh = (unsigned)hi | (nh << 16);
    unsigned wl = (unsigned)lo | (nl << 16);
    __hip_atomic_store((unsigned*)(slot + eo), wh, __ATOMIC_RELAXED, __HIP_MEMORY_SCOPE_AGENT);
    __hip_atomic_store((unsigned*)(slot + PLANE + eo), wl, __ATOMIC_RELAXED, __HIP_MEMORY_SCOPE_AGENT);
  }
}

// convert 8 f32 (cached loads) -> bf16 hi/lo fragments (stage A x-path)
__device__ __forceinline__ void xcvt(const float* xp, short8& ah, short8& al) {
  f32x4 v0 = *(const f32x4*)xp;
  f32x4 v1 = *(const f32x4*)(xp + 4);
#pragma unroll
  for (int i = 0; i < 4; ++i) {
    ushort_t h0 = f2bf(v0[i]);
    ah[i] = (short)h0; al[i] = (short)f2bf(v0[i] - bf2f(h0));
    ushort_t h1 = f2bf(v1[i]);
    ah[i + 4] = (short)h1; al[i + 4] = (short)f2bf(v1[i] - bf2f(h1));
  }
}

// ---------------- prep: transpose + hi/lo split weights; convert h0 ---------
extern "C" __global__ void prep_kernel(const float* __restrict__ W0,
                                       const float* __restrict__ Ws,
                                       const float* __restrict__ h0,
                                       char* __restrict__ ws) {
  ushort_t* w0h = (ushort_t*)(ws + WS_W0T_HI);
  ushort_t* w0l = (ushort_t*)(ws + WS_W0T_LO);
  ushort_t* wsh = (ushort_t*)(ws + WS_WST_HI);
  ushort_t* wsl = (ushort_t*)(ws + WS_WST_LO);
  ushort_t* st  = (ushort_t*)(ws + WS_ST);
  const long N0 = 1048576, N1 = 4194304, N2 = 131072;
  long total = N0 + N1 + N2;
  for (long idx = (long)blockIdx.x * blockDim.x + threadIdx.x; idx < total;
       idx += (long)gridDim.x * blockDim.x) {
    if (idx < N0) {                       // W0T[j][k] from W0[k][j], K=1024
      int k = (int)(idx >> 10), j = (int)(idx & 1023);
      float v = W0[k * 1024 + j];
      ushort_t hi = f2bf(v);
      w0h[j * 1024 + k] = hi;
      w0l[j * 1024 + k] = f2bf(v - bf2f(hi));
    } else if (idx < N0 + N1) {           // WsT[i][j][k] from Ws[i][k][j], K=512
      long r = idx - N0;
      int i = (int)(r >> 19);
      int r2 = (int)(r & 524287);
      int k = r2 >> 10, j = r2 & 1023;
      float v = Ws[(long)i * 524288 + k * 1024 + j];
      ushort_t hi = f2bf(v);
      wsh[(long)i * 524288 + j * 512 + k] = hi;
      wsl[(long)i * 524288 + j * 512 + k] = f2bf(v - bf2f(hi));
    } else {                              // h0 -> slot 0 (linear)
      int e = (int)(idx - N0 - N1);
      float v = h0[e];
      ushort_t hi = f2bf(v);
      st[e] = hi;
      st[PLANE + e] = f2bf(v - bf2f(hi));
    }
  }
}

// ---- producer-flag sync: 16 groups x 16 producers --------------------------
__device__ __forceinline__ void set_flag(unsigned* flags, int g, int pt, unsigned gen) {
  __syncthreads();   // drains each wave's vmcnt: uncached stores coherent-visible
  if (threadIdx.x == 0)
    __hip_atomic_store(flags + (g * 16 + pt) * 16, gen, __ATOMIC_RELAXED, __HIP_MEMORY_SCOPE_AGENT);
}
// each thread polls the 2 producers of its panel chunks
__device__ __forceinline__ void panel_poll2(const unsigned* flags, int g, unsigned G, int tid) {
  const int q = (tid & 31) >> 2;          // producer of cols [8i,8i+8): i>>2
  const unsigned* f0 = flags + (g * 16 + q) * 16;
  const unsigned* f1 = flags + (g * 16 + 8 + q) * 16;
  while (__hip_atomic_load(f0, __ATOMIC_RELAXED, __HIP_MEMORY_SCOPE_AGENT) < G)
    __builtin_amdgcn_s_sleep(2);
  while (__hip_atomic_load(f1, __ATOMIC_RELAXED, __HIP_MEMORY_SCOPE_AGENT) < G)
    __builtin_amdgcn_s_sleep(2);
}

// ---- panel: [kc(64)][rowslot(16)][8] shorts, XOR-swizzled rowslot = row^(kc&15)
// 16 rows x 512 cols, hi/lo planes (verified R11/R12).
__device__ __forceinline__ void panel_copy(const ushort_t* slot, int r0,
                                           ushort_t* Ph, ushort_t* Pl, int tid) {
  const int row = tid >> 5, i = tid & 31;
  const ushort_t* src = slot + (r0 + row) * 512;
  u32x4 h0 = uld16(src + i * 8);
  u32x4 h1 = uld16(src + 256 + i * 8);
  u32x4 l0 = uld16(src + PLANE + i * 8);
  u32x4 l1 = uld16(src + PLANE + 256 + i * 8);
  asm volatile("s_waitcnt vmcnt(0)" ::: "memory");
  __builtin_amdgcn_sched_barrier(0);      // rule #18
  const int kc0 = i, kc1 = i + 32;
  *(u32x4*)(Ph + kc0 * 128 + ((row ^ (kc0 & 15)) << 3)) = h0;
  *(u32x4*)(Ph + kc1 * 128 + ((row ^ (kc1 & 15)) << 3)) = h1;
  *(u32x4*)(Pl + kc0 * 128 + ((row ^ (kc0 & 15)) << 3)) = l0;
  *(u32x4*)(Pl + kc1 * 128 + ((row ^ (kc1 & 15)) << 3)) = l1;
}

__device__ __forceinline__ f32x4 mfma3_4(short8 ah, short8 al, short8 bh, short8 bl, f32x4 acc) {
  acc = __builtin_amdgcn_mfma_f32_16x16x32_bf16(ah, bh, acc, 0, 0, 0);
  acc = __builtin_amdgcn_mfma_f32_16x16x32_bf16(ah, bl, acc, 0, 0, 0);
  acc = __builtin_amdgcn_mfma_f32_16x16x32_bf16(al, bh, acc, 0, 0, 0);
  return acc;
}

// wave (ct,kh) accumulates its 16-col tile x K-half against NP weight matrices.
// bofs = j*K + kh*256 + (lane>>4)*8 (caller), panel A-frags swizzle-read.
template<int NP>
__device__ __forceinline__ void mmW(const ushort_t* Ph, const ushort_t* Pl,
                                    const ushort_t* const (&wh)[NP],
                                    const ushort_t* const (&wl)[NP],
                                    int bofs, int kh, int lane,
                                    f32x4 (&acc)[NP]) {
#pragma unroll
  for (int ks = 0; ks < 8; ++ks) {
    const int klocal = kh * 256 + ks * 32 + ((lane >> 4) << 3);
    const int kc = klocal >> 3;
    const int po = kc * 128 + (((lane & 15) ^ (kc & 15)) << 3);
    short8 ah = *(const short8*)(Ph + po);
    short8 al = *(const short8*)(Pl + po);
#pragma unroll
    for (int p = 0; p < NP; ++p) {
      short8 bh = *(const short8*)(wh[p] + bofs + ks * 32);
      short8 bl = *(const short8*)(wl[p] + bofs + ks * 32);
      acc[p] = mfma3_4(ah, al, bh, bl, acc[p]);
    }
  }
}

// pp[blk(kh*4+ct)][16][18] f32 (9216B); 16x16 C/D: col=lane&15, row=(lane>>4)*4+r
__device__ __forceinline__ void wrp(float* pp, int blk, const f32x4& a, int lane) {
  float* b = pp + blk * 288 + (lane & 15);
  const int rb = (lane >> 4) * 4;
#pragma unroll
  for (int r = 0; r < 4; ++r) b[(rb + r) * 18] = a[r];
}
// thread owns (erow, gate-pair gp): c from tiles {0,1}, h from tiles {2,3}; sum 2 kh
__device__ __forceinline__ void rdp(const float* pp, int erow, int gp,
                                    float& c, float& h) {
  const int tc = gp >> 4, n = gp & 15;
  c = pp[(tc) * 288 + erow * 18 + n]     + pp[(4 + tc) * 288 + erow * 18 + n];
  h = pp[(2 + tc) * 288 + erow * 18 + n] + pp[(6 + tc) * 288 + erow * 18 + n];
}

// ---------------- main persistent kernel -----------------------------------
extern "C" __global__ void __launch_bounds__(512, 1)
rnn_main(const float* __restrict__ x, float* __restrict__ out, char* __restrict__ ws) {
  __shared__ __align__(16) ushort_t Ph[8192];   // 16 KB panel hi (swizzled)
  __shared__ __align__(16) ushort_t Pl[8192];   // 16 KB panel lo
  __shared__ __align__(16) float pp0[2304];     // 9 KB partials (matrix 0)
  __shared__ __align__(16) float pp1[2304];     // 9 KB partials (matrix 1)

  ushort_t* stg = (ushort_t*)(ws + WS_ST);
  unsigned* flags = (unsigned*)(ws + WS_BAR);
  const ushort_t* w0h = (const ushort_t*)(ws + WS_W0T_HI);
  const ushort_t* w0l = (const ushort_t*)(ws + WS_W0T_LO);
  const ushort_t* wsh = (const ushort_t*)(ws + WS_WST_HI);
  const ushort_t* wsl = (const ushort_t*)(ws + WS_WST_LO);

  const int tid = threadIdx.x;
  const int wg = blockIdx.x;
  const int g = wg >> 4, pt = wg & 15;    // 16 row-groups x 16 col-WGs; XCD = pt%8
  const int r0 = g * 16;
  const int w = tid >> 6, lane = tid & 63;
  const int ct = w >> 1, kh = w & 1;      // 4 col-tiles x 2 K-halves
  const int j = ((ct < 2) ? (pt * 32 + ct * 16)
                          : (512 + pt * 32 + (ct - 2) * 16)) + (lane & 15);
  const int lk8 = (lane >> 4) << 3;
  const int bofs5  = j * 512 + kh * 256 + lk8;         // Ws matrices
  const int bofsAx = j * 1024 + kh * 256 + lk8;        // W0 x-part
  const int bofsAh = j * 1024 + 512 + kh * 256 + lk8;  // W0 h-part

  const int erow = tid >> 5, gp = tid & 31;   // thread's owned output element
  const int eo = (r0 + erow) * 512 + pt * 32 + gp;

  float h_reg = bf2f(stg[eo]) + bf2f(stg[PLANE + eo]);
  float s0 = 0, s1 = 0, s2 = 0, s3 = 0, s5 = 0, sum = 0;

  for (int t = 0; t < 400; ++t) {
    const unsigned base = 5u * (unsigned)t;

    // ===== stage A: s0 = h + sig(c)*(tanh(hh) - h), A=[x|h], W0 ============
    {
      f32x4 acc[1] = {};
      const float* xr = x + (size_t)t * 131072 + (size_t)(r0 + (lane & 15)) * 512;
#pragma unroll
      for (int ks = 0; ks < 8; ++ks) {    // x-part: cached, no flag dependency
        const int k = kh * 256 + ks * 32 + lk8;
        short8 xh8, xl8; xcvt(xr + k, xh8, xl8);
        short8 bh = *(const short8*)(w0h + bofsAx + ks * 32);
        short8 bl = *(const short8*)(w0l + bofsAx + ks * 32);
        acc[0] = mfma3_4(xh8, xl8, bh, bl, acc[0]);
      }
      panel_poll2(flags, g, base, tid);   // E flags of t-1 (h producers)
      panel_copy(stg + 0 * SLOT_ELEMS, r0, Ph, Pl, tid);
      __syncthreads();
      const ushort_t* wh1[1] = {w0h};
      const ushort_t* wl1[1] = {w0l};
      mmW<1>(Ph, Pl, wh1, wl1, bofsAh, kh, lane, acc);
      wrp(pp0, kh * 4 + ct, acc[0], lane);
      __syncthreads();
      float c, hh; rdp(pp0, erow, gp, c, hh);
      s0 = h_reg + sigf(c) * (tanhf(hh) - h_reg);
      st_state(stg + 1 * SLOT_ELEMS, eo, s0, tid);
    }
    set_flag(flags, g, pt, base + 1);

    // ===== stage B: s1 = f(s0, tanh, Ws[0]) ================================
    {
      panel_poll2(flags, g, base + 1, tid);
      panel_copy(stg + 1 * SLOT_ELEMS, r0, Ph, Pl, tid);
      __syncthreads();
      f32x4 acc[1] = {};
      const ushort_t* wh1[1] = {wsh + 0 * 524288};
      const ushort_t* wl1[1] = {wsl + 0 * 524288};
      mmW<1>(Ph, Pl, wh1, wl1, bofs5, kh, lane, acc);
      wrp(pp0, kh * 4 + ct, acc[0], lane);
      __syncthreads();
      float c, hh; rdp(pp0, erow, gp, c, hh);
      s1 = s0 + sigf(c) * (tanhf(hh) - s0);
      sum = s1;
      st_state(stg + 2 * SLOT_ELEMS, eo, s1, tid);
    }
    set_flag(flags, g, pt, base + 2);

    // ===== stage C: s2(relu,Ws1) s3(relu,Ws2) s4(ident,Ws3) from s1 ========
    {
      panel_poll2(flags, g, base + 2, tid);
      panel_copy(stg + 2 * SLOT_ELEMS, r0, Ph, Pl, tid);
      __syncthreads();
      f32x4 acc[3] = {};
      const ushort_t* wh3[3] = {wsh + 1 * 524288, wsh + 2 * 524288, wsh + 3 * 524288};
      const ushort_t* wl3[3] = {wsl + 1 * 524288, wsl + 2 * 524288, wsl + 3 * 524288};
      mmW<3>(Ph, Pl, wh3, wl3, bofs5, kh, lane, acc);
      wrp(pp0, kh * 4 + ct, acc[0], lane);   // s2
      wrp(pp1, kh * 4 + ct, acc[1], lane);   // s3
      __syncthreads();
      float c, hh;
      rdp(pp0, erow, gp, c, hh);
      s2 = s1 + sigf(c) * (fmaxf(hh, 0.f) - s1);
      sum += s2;
      st_state(stg + 3 * SLOT_ELEMS, eo, s2, tid);
      rdp(pp1, erow, gp, c, hh);
      s3 = s1 + sigf(c) * (fmaxf(hh, 0.f) - s1);
      sum += s3;
      st_state(stg + 4 * SLOT_ELEMS, eo, s3, tid);
      set_flag(flags, g, pt, base + 3);      // early: D needs only s2/s3 (sync inside)
      wrp(pp0, kh * 4 + ct, acc[2], lane);   // s4: concat-only
      __syncthreads();
      rdp(pp0, erow, gp, c, hh);
      sum += s1 + sigf(c) * (hh - s1);
    }

    // ===== stage D: s5 = f(s2,tanh,Ws4); s7 = f(s3,tanh,Ws6) — one poll ====
    {
      panel_poll2(flags, g, base + 3, tid);
      panel_copy(stg + 3 * SLOT_ELEMS, r0, Ph, Pl, tid);   // s2 panel
      __syncthreads();                    // also fences s4's pp0 reads
      f32x4 acc5[1] = {};
      const ushort_t* wh4[1] = {wsh + 4 * 524288};
      const ushort_t* wl4[1] = {wsl + 4 * 524288};
      mmW<1>(Ph, Pl, wh4, wl4, bofs5, kh, lane, acc5);
      wrp(pp1, kh * 4 + ct, acc5[0], lane);   // pp1 free since C's set_flag sync
      __syncthreads();                    // panel reads done before recopy
      panel_copy(stg + 4 * SLOT_ELEMS, r0, Ph, Pl, tid);   // s3 panel
      __syncthreads();
      f32x4 acc7[1] = {};
      const ushort_t* wh6[1] = {wsh + 6 * 524288};
      const ushort_t* wl6[1] = {wsl + 6 * 524288};
      mmW<1>(Ph, Pl, wh6, wl6, bofs5, kh, lane, acc7);
      wrp(pp0, kh * 4 + ct, acc7[0], lane);   // pp0's s4 reads fenced 2 syncs ago
      __syncthreads();
      float c, hh;
      rdp(pp1, erow, gp, c, hh);
      s5 = s2 + sigf(c) * (tanhf(hh) - s2);
      sum += s5;
      st_state(stg + 5 * SLOT_ELEMS, eo, s5, tid);
      rdp(pp0, erow, gp, c, hh);          // s7: concat-only
      sum += s3 + sigf(c) * (tanhf(hh) - s3);
    }
    set_flag(flags, g, pt, base + 4);

    // ===== stage E: s6(sigmoid,Ws5) s8(relu,Ws7) from s5; mean; h ==========
    {
      panel_poll2(flags, g, base + 4, tid);
      panel_copy(stg + 5 * SLOT_ELEMS, r0, Ph, Pl, tid);
      __syncthreads();
      f32x4 acc[2] = {};
      const ushort_t* wh2[2] = {wsh + 5 * 524288, wsh + 7 * 524288};
      const ushort_t* wl2[2] = {wsl + 5 * 524288, wsl + 7 * 524288};
      mmW<2>(Ph, Pl, wh2, wl2, bofs5, kh, lane, acc);
      wrp(pp0, kh * 4 + ct, acc[0], lane);   // s6 (pp0 free since set_flag sync)
      wrp(pp1, kh * 4 + ct, acc[1], lane);   // s8 (pp1 free likewise)
      __syncthreads();
      float c, hh;
      rdp(pp0, erow, gp, c, hh);
      sum += s5 + sigf(c) * (sigf(hh) - s5);
      rdp(pp1, erow, gp, c, hh);
      sum += s5 + sigf(c) * (fmaxf(hh, 0.f) - s5);
      h_reg = sum * 0.125f;
      __builtin_nontemporal_store(h_reg, &out[(size_t)t * 131072 + eo]);
      if (t == 399)
        __builtin_nontemporal_store(h_reg, &out[(size_t)400 * 131072 + eo]);
      st_state(stg + 0 * SLOT_ELEMS, eo, h_reg, tid);
    }
    set_flag(flags, g, pt, base + 5);
  }
}

// ---------------- host launch ----------------------------------------------
extern "C" void kernel_launch(void* const* d_in, const int* in_sizes, int n_in,
                              void* d_out, int out_size, void* d_ws, size_t ws_size,
                              hipStream_t stream) {
  const float* x  = (const float*)d_in[0];
  const float* h0 = (const float*)d_in[1];
  const float* W0 = (const float*)d_in[2];
  const float* Ws = (const float*)d_in[3];
  float* out = (float*)d_out;
  char* ws = (char*)d_ws;

  (void)in_sizes; (void)n_in; (void)out_size; (void)ws_size;

  (void)hipMemsetAsync(ws + WS_BAR, 0, 32768, stream);
  hipLaunchKernelGGL(prep_kernel, dim3(2048), dim3(256), 0, stream, W0, Ws, h0, ws);

  void* args[3] = {(void*)&x, (void*)&out, (void*)&ws};
  hipError_t e = hipLaunchCooperativeKernel((void*)rnn_main, dim3(256), dim3(512),
                                            args, 0, stream);
  if (e != hipSuccess) {
    (void)hipGetLastError();
    hipLaunchKernelGGL(rnn_main, dim3(256), dim3(512), 0, stream, x, out, ws);
  }
}